// Round 3
// baseline (372.723 us; speedup 1.0000x reference)
//
#include <hip/hip_runtime.h>
#include <hip/hip_bf16.h>

#define TT 512
#define BB 256
#define NN 128

// Linear-space forward algorithm, one workgroup (4 waves) per batch element.
// State W[j] = exp(u[j] - L) lives in LDS (double-buffered); per step:
//   S[j] = sum_i W[i] E[i][j]   (split-K: waves 0,1 -> i<64; waves 2,3 -> i>=64)
//   W'[j] = S[j] * exp(emit_t[j]) * rcp(W[0]);   L += log(W[0])
// exp(emit) precomputed in the prefetch window; log(W[0]) off the critical
// path. No exp/log on the serial chain.
__global__ __launch_bounds__(256, 1) void crf_forward(
    const float* __restrict__ emit, const void* __restrict__ maskp,
    const float* __restrict__ trans, const float* __restrict__ strans,
    const float* __restrict__ etrans, float* __restrict__ ws) {
  __shared__ __align__(16) float sh_p[2][NN];
  __shared__ __align__(8) float sh_part[2 * NN];  // [2*j + h]
  __shared__ float sh_u00;
  __shared__ int sh_ri[4];
  __shared__ float sh_rf[2];

  const int tid = threadIdx.x;
  const int b = blockIdx.x;
  const int j = tid & (NN - 1);
  const int h = tid >> 7;               // split-K half
  const bool combine = (tid < NN);      // waves 0,1 own state j

  // ---- mask dtype detection + sequence length ----
  const unsigned char* mk8 = (const unsigned char*)maskp;
  const int* mk32 = (const int*)maskp;
  const bool is_u8 = (mk8[1] != 0);
  int cnt = 0;
  for (int t = tid; t < TT; t += 256) {
    int m = is_u8 ? (mk8[t * BB + b] != 0) : (mk32[t * BB + b] != 0);
    cnt += m;
  }
#pragma unroll
  for (int off = 32; off; off >>= 1) cnt += __shfl_down(cnt, off, 64);
  if ((tid & 63) == 0) sh_ri[tid >> 6] = cnt;
  __syncthreads();
  const int len = sh_ri[0] + sh_ri[1] + sh_ri[2] + sh_ri[3];

  // ---- E = exp(trans) in registers: e[k] = exp(trans[h*64+k][j]) ----
  float e[64];
#pragma unroll
  for (int k = 0; k < 64; ++k)
    e[k] = __expf(trans[(h * 64 + k) * NN + j]);

  // ---- init: W_0[j] = exp(u0[j] - u0[0]), L = u0[0] ----
  float u0 = 0.f, w = 0.f, L = 0.f;
  if (combine) u0 = strans[j] + emit[(size_t)b * NN + j];
  if (tid == 0) sh_u00 = u0;
  __syncthreads();
  if (combine) {
    L = sh_u00;
    w = __expf(u0 - L);
    sh_p[0][j] = w;
  }

  // ---- prefetch emit rows for first group (t = 1..8) + exp them ----
  float ebuf[8], xbuf[8];
  if (combine) {
#pragma unroll
    for (int k = 0; k < 8; ++k) {
      int t = 1 + k;
      ebuf[k] = (t < TT) ? emit[((size_t)t * BB + b) * NN + j] : 0.f;
    }
#pragma unroll
    for (int k = 0; k < 8; ++k) xbuf[k] = __expf(ebuf[k]);
  }
  __syncthreads();  // W_0 visible to all

  const int ngroups = (len + 6) / 8;  // steps t = 1..len-1
  for (int g = 0; g < ngroups; ++g) {
    const int tbase = 1 + g * 8;

    float enext[8];
    if (combine) {
#pragma unroll
      for (int k = 0; k < 8; ++k) {
        int t = tbase + 8 + k;
        enext[k] = (t < TT) ? emit[((size_t)t * BB + b) * NN + j] : 0.f;
      }
    }

#pragma unroll
    for (int k = 0; k < 8; ++k) {
      const int t = tbase + k;
      const int in = (t - 1) & 1;
      const int out = t & 1;

      // split-K dot over this wave's half of W (broadcast b128 reads)
      const float4* p4 = reinterpret_cast<const float4*>(sh_p[in]) + h * 16;
      float4 v0 = p4[0], v1 = p4[1], v2 = p4[2], v3 = p4[3];
      const float p00 = v0.x;  // = W_in[0] for h==0 (combine waves)
      float a0 = 0.f, a1 = 0.f, a2 = 0.f, a3 = 0.f;
#pragma unroll
      for (int c = 0; c < 16; c += 4) {
        a0 = fmaf(v0.x, e[4 * c + 0], a0);
        a0 = fmaf(v0.y, e[4 * c + 1], a0);
        a0 = fmaf(v0.z, e[4 * c + 2], a0);
        a0 = fmaf(v0.w, e[4 * c + 3], a0);
        a1 = fmaf(v1.x, e[4 * c + 4], a1);
        a1 = fmaf(v1.y, e[4 * c + 5], a1);
        a1 = fmaf(v1.z, e[4 * c + 6], a1);
        a1 = fmaf(v1.w, e[4 * c + 7], a1);
        a2 = fmaf(v2.x, e[4 * c + 8], a2);
        a2 = fmaf(v2.y, e[4 * c + 9], a2);
        a2 = fmaf(v2.z, e[4 * c + 10], a2);
        a2 = fmaf(v2.w, e[4 * c + 11], a2);
        a3 = fmaf(v3.x, e[4 * c + 12], a3);
        a3 = fmaf(v3.y, e[4 * c + 13], a3);
        a3 = fmaf(v3.z, e[4 * c + 14], a3);
        a3 = fmaf(v3.w, e[4 * c + 15], a3);
        if (c + 4 < 16) {
          v0 = p4[c + 4];
          v1 = p4[c + 5];
          v2 = p4[c + 6];
          v3 = p4[c + 7];
        }
      }
      sh_part[2 * j + h] = (a0 + a1) + (a2 + a3);
      __syncthreads();  // barrier B: partials visible

      if (combine) {
        float s0 = sh_part[2 * j];
        float s1 = sh_part[2 * j + 1];
        if (t < len) {
          float r = __builtin_amdgcn_rcpf(p00);
          w = (s0 + s1) * xbuf[k] * r;
          sh_p[out][j] = w;
          L += __logf(p00);
        }
      }
      __syncthreads();  // barrier A for next step: W' visible / parts reusable
    }

    if (combine) {
#pragma unroll
      for (int k = 0; k < 8; ++k) ebuf[k] = enext[k];
#pragma unroll
      for (int k = 0; k < 8; ++k) xbuf[k] = __expf(ebuf[k]);
    }
  }

  // ---- final: logZ_b = L + log(sum_j W[j] * exp(etrans[j])) ----
  float y = 0.f;
  if (combine) y = w * __expf(etrans[j]);
#pragma unroll
  for (int off = 32; off; off >>= 1) y += __shfl_down(y, off, 64);
  if (combine && (tid & 63) == 0) sh_rf[tid >> 6] = y;
  __syncthreads();
  if (tid == 0) {
    float s = sh_rf[0] + sh_rf[1];
    atomicAdd(&ws[0], L + __logf(s));
  }
}

// Gold-path score: block = batch dim (coalesced), grid = time dim.
// End transition detected via prefix-mask edge (mask[t] && !mask[t+1]).
__global__ __launch_bounds__(256) void crf_score(
    const float* __restrict__ emit, const int* __restrict__ target,
    const void* __restrict__ maskp, const float* __restrict__ trans,
    const float* __restrict__ strans, const float* __restrict__ etrans,
    float* __restrict__ ws) {
  __shared__ float rf[4];
  const int b = threadIdx.x;
  const int t = blockIdx.x;
  const unsigned char* mk8 = (const unsigned char*)maskp;
  const int* mk32 = (const int*)maskp;
  const bool is_u8 = (mk8[1] != 0);

  int m = is_u8 ? (mk8[t * BB + b] != 0) : (mk32[t * BB + b] != 0);
  float v = 0.f;
  if (m) {
    int tg = target[t * BB + b];
    v = emit[((size_t)t * BB + b) * NN + tg];
    if (t > 0)
      v += trans[target[(t - 1) * BB + b] * NN + tg];
    else
      v += strans[tg];
    int mnext = (t + 1 < TT)
                    ? (is_u8 ? (mk8[(t + 1) * BB + b] != 0)
                             : (mk32[(t + 1) * BB + b] != 0))
                    : 0;
    if (!mnext) v += etrans[tg];
  }
#pragma unroll
  for (int off = 32; off; off >>= 1) v += __shfl_down(v, off, 64);
  if ((b & 63) == 0) rf[b >> 6] = v;
  __syncthreads();
  if (b == 0) atomicAdd(&ws[1], rf[0] + rf[1] + rf[2] + rf[3]);
}

__global__ void crf_fin(const float* __restrict__ ws, float* __restrict__ out) {
  out[0] = (ws[0] - ws[1]) * (1.0f / (float)BB);
}

extern "C" void kernel_launch(void* const* d_in, const int* in_sizes, int n_in,
                              void* d_out, int out_size, void* d_ws, size_t ws_size,
                              hipStream_t stream) {
  const float* emit = (const float*)d_in[0];
  const int* target = (const int*)d_in[1];
  const void* mask = (const void*)d_in[2];
  const float* trans = (const float*)d_in[3];
  const float* strans = (const float*)d_in[4];
  const float* etrans = (const float*)d_in[5];
  float* ws = (float*)d_ws;
  float* out = (float*)d_out;

  hipMemsetAsync(d_ws, 0, 2 * sizeof(float), stream);
  crf_forward<<<BB, 256, 0, stream>>>(emit, mask, trans, strans, etrans, ws);
  crf_score<<<TT, BB, 0, stream>>>(emit, target, mask, trans, strans, etrans, ws);
  crf_fin<<<1, 1, 0, stream>>>(ws, out);
}